// Round 1
// baseline (1083.367 us; speedup 1.0000x reference)
//
#include <hip/hip_runtime.h>
#include <hip/hip_bf16.h>
#include <stdint.h>

#define DEV __device__ __forceinline__

typedef __attribute__((ext_vector_type(8))) short short8;   // 8 bf16 (4 VGPRs)
typedef __attribute__((ext_vector_type(4))) float floatx4;  // MFMA acc

DEV unsigned short f2bf(float f) {  // round-to-nearest-even fp32 -> bf16
  union { float f; unsigned u; } v; v.f = f;
  return (unsigned short)((v.u + 0x7fffu + ((v.u >> 16) & 1u)) >> 16);
}
DEV float bf2f(unsigned short s) {
  union { unsigned u; float f; } v; v.u = ((unsigned)s) << 16; return v.f;
}
DEV float sigmoid_f(float x) { return 1.0f / (1.0f + __expf(-x)); }
DEV float tanh_f(float x) { return 1.0f - 2.0f / (__expf(2.0f * x) + 1.0f); }

// async global->LDS, 16B per lane; vmcnt-tracked. LDS dest is wave-uniform
// base + lane*16B (required); global src is per-lane.
DEV void glds16(const unsigned short* g, unsigned short* l) {
  __builtin_amdgcn_global_load_lds(
      (const __attribute__((address_space(1))) unsigned int*)g,
      (__attribute__((address_space(3))) unsigned int*)l, 16, 0, 0);
}

// Cross-WG visible store: bf16 pair packed to a dword, relaxed agent-scope.
DEV void store_pair_coh(unsigned* p, unsigned v) {
  __hip_atomic_store(p, v, __ATOMIC_RELAXED, __HIP_MEMORY_SCOPE_AGENT);
}

// Per-group (32 WG) ticket barrier. __syncthreads drains vmcnt(0)/lgkmcnt(0)
// (all data stores complete & counters clean) before thread0 arrives.
DEV void groupbar(unsigned* slot) {
  __syncthreads();
  if (threadIdx.x == 0) {
    __hip_atomic_fetch_add(slot, 1u, __ATOMIC_RELAXED, __HIP_MEMORY_SCOPE_AGENT);
    while (__hip_atomic_load(slot, __ATOMIC_RELAXED, __HIP_MEMORY_SCOPE_AGENT) < 32u)
      __builtin_amdgcn_s_sleep(1);
  }
  __syncthreads();
}

// Counted-wait pipeline primitives (T3/T4: never drain vmcnt mid-phase).
#define WAIT_VM(N) asm volatile("s_waitcnt vmcnt(" #N ")" ::: "memory")
#define WAIT_LGKM0 asm volatile("s_waitcnt lgkmcnt(0)" ::: "memory")
#define BAR __builtin_amdgcn_s_barrier()
#define PIN asm volatile("" ::: "memory")

// ---------------------------------------------------------------------------
// Persistent recurrence: 256 WGs x 256 thr, 1 WG/CU. n = blockIdx&31 (output
// col slice; n%8 = XCD so weight slices are XCD-local), g = blockIdx>>5
// (batch rows 32g..+31). Recurrent h carried in REGISTERS (hp[4]); Whu/Whr
// weight fragments REGISTER-RESIDENT (BU/BR: 256 VGPR) -> phase A stages only
// the 64KB h-tile, issued fully upfront into the whole 64KB LDS and consumed
// with counted vmcnt waits + raw s_barrier (no mid-phase vmcnt(0) drain).
// Phase B streams rh (64KB, L3) + Wh (64KB, L2-resident) in two 64KB halves,
// same counted-wait schedule. Cross-WG state: hbf ring (write-once slices) +
// rhbf ring; groupbar (per-g, 32 WGs) drains all counters at phase edges so
// every pipelined window contains exactly the 16 staging loads it counts
// (extra compiler vmem ops only make the waits more conservative).
// ---------------------------------------------------------------------------
__global__ __launch_bounds__(256, 1) void k_recur(
    const unsigned short* __restrict__ XPur, const unsigned short* __restrict__ Whhc,
    float* __restrict__ out, float* __restrict__ h,
    unsigned short* __restrict__ hbfR, unsigned short* __restrict__ rhbfR,
    const float* __restrict__ b_h, unsigned* __restrict__ bar) {
  __shared__ __align__(16) unsigned short lds[32768];  // 64 KB
  const int tid = threadIdx.x;
  const int w = tid >> 6, l = tid & 63;
  const int l15 = l & 15, l4 = l >> 4;
  const int wm = w >> 1, wn = w & 1;
  const int n = blockIdx.x & 31, g = blockIdx.x >> 5;
  const int R0 = g * 32, C0B = n * 32;
  unsigned* slots = bar + g * 128;
  unsigned* hbfRu = (unsigned*)hbfR;
  const unsigned short* WhT = Whhc + (size_t)2048 * 1024;
  const floatx4 z = {0.f, 0.f, 0.f, 0.f};

  // ---- register-resident u/r weight fragments (one-time L2 stream) ----
  // BU[kg]/BR[kg]: lane l holds W[(C0B + wn*16 + l15)][kg*32 + l4*8 .. +8]
  // == exactly the MFMA B-operand fragment layout previously staged via LDS.
  short8 BU[32], BR[32];
#pragma unroll
  for (int kg = 0; kg < 32; kg++) {
    BU[kg] = *(const short8*)(Whhc + (size_t)(C0B + wn * 16 + l15) * 1024 + kg * 32 + l4 * 8);
    BR[kg] = *(const short8*)(Whhc + (size_t)(1024 + C0B + wn * 16 + l15) * 1024 + kg * 32 + l4 * 8);
  }

  // ---- h0 = tanh(XPi[t=0]); k_pre staged XPi+b_i into out[b][0][:] ----
  {
    const int col0 = C0B + (tid & 31);
    const int rb = R0 + (tid >> 5);
#pragma unroll
    for (int r4 = 0; r4 < 4; r4++) {
      const int row = rb + r4 * 8;
      const size_t oidx = (size_t)row * 65536 + col0;
      const float v = tanh_f(out[oidx]);
      out[oidx] = v;
      h[row * 1024 + col0] = v;  // one-time handoff to the reg-carried hp
      const unsigned mv = (unsigned)f2bf(v);
      const unsigned ov = (unsigned)__shfl_xor((int)mv, 1, 64);
      if ((tid & 1) == 0)
        store_pair_coh(hbfRu + row * 512 + (col0 >> 1), mv | (ov << 16));
    }
  }
  groupbar(slots + 1);

  const int col = C0B + wn * 16 + l15;      // this wave's output col
  const int erow0 = R0 + wm * 16 + l4 * 4;  // C/D layout row base
  const float bhv = b_h[col];

  // recurrent state in registers (private: only this WG computes these cells)
  float hp[4];
#pragma unroll
  for (int r = 0; r < 4; r++) hp[r] = h[(erow0 + r) * 1024 + col];

  unsigned short xpu[4], xpr[4];
  {
    const unsigned short* XPt = XPur + (size_t)1 * 524288;
#pragma unroll
    for (int r = 0; r < 4; r++) {
      xpu[r] = XPt[(size_t)(erow0 + r) * 2048 + col];
      xpr[r] = XPt[(size_t)(erow0 + r) * 2048 + 1024 + col];
    }
  }

  for (int t = 1; t < 64; t++) {
    const unsigned short* hbfPrev = hbfR + (size_t)(t - 1) * 262144;
    unsigned short* rhbfT = rhbfR + (size_t)(t & 15) * 262144;
    unsigned* rhbfTu = (unsigned*)rhbfT;
    float uu[4], xpi[4];

    // ========== phase A: u (regs) and r -> rhbf[t] ==========
    // Stage the full 32x1024 h-tile (64 frags of 16rows x 32k = 1KB) into all
    // of LDS, issued upfront; consume in 4 supergroups of 8 kg.
    {
      PIN;
#pragma unroll
      for (int sc = 0; sc < 4; sc++)
#pragma unroll
        for (int q = 0; q < 4; q++) {
          const int f = q * 4 + w;             // 16 frags per supergroup
          const int kg = sc * 8 + (f >> 1);
          const int rg = f & 1;
          glds16(hbfPrev + (size_t)(R0 + rg * 16 + l15) * 1024 + kg * 32 + l4 * 8,
                 lds + (kg * 2 + rg) * 512);
        }
      floatx4 acc_u = z, acc_r = z;
#define A_SC(sc)                                                               \
  _Pragma("unroll") for (int j = 0; j < 8; j++) {                              \
    const int kg = (sc) * 8 + j;                                               \
    const short8 a = *(const short8*)(lds + (kg * 2 + wm) * 512 + l * 8);      \
    acc_u = __builtin_amdgcn_mfma_f32_16x16x32_bf16(a, BU[kg], acc_u, 0, 0, 0);\
    acc_r = __builtin_amdgcn_mfma_f32_16x16x32_bf16(a, BR[kg], acc_r, 0, 0, 0);\
  }
      WAIT_VM(12); BAR; PIN; A_SC(0)
      WAIT_VM(8);  BAR; PIN; A_SC(1)
      WAIT_VM(4);  BAR; PIN; A_SC(2)
      WAIT_VM(0);  BAR; PIN; A_SC(3)
#undef A_SC
#pragma unroll
      for (int r = 0; r < 4; r++) {
        uu[r] = sigmoid_f(acc_u[r] + bf2f(xpu[r]));
        const float rr = sigmoid_f(acc_r[r] + bf2f(xpr[r]));
        const unsigned mv = (unsigned)f2bf(rr * hp[r]);
        const unsigned ov = (unsigned)__shfl_xor((int)mv, 1, 64);
        if ((l & 1) == 0)
          store_pair_coh(rhbfTu + (erow0 + r) * 512 + (col >> 1), mv | (ov << 16));
      }
    }
    // hoist xpi loads under the barrier (private slice, written by k_pre)
#pragma unroll
    for (int r = 0; r < 4; r++)
      xpi[r] = out[((size_t)(erow0 + r) * 64 + t) * 1024 + col];
    groupbar(slots + 2 * t);

    // ========== phase B: cand = tanh(rh@Wh + xpi + bh); update ==========
    // Two 64KB halves (K=0..511, 512..1023): each = rh 32KB + Wh 32KB,
    // issued upfront, consumed in 4 supergroups of 4 kg.
    {
      floatx4 acc_c = z;
#define ISSUE_B(h_)                                                            \
  _Pragma("unroll") for (int sc = 0; sc < 4; sc++)                             \
  _Pragma("unroll") for (int q = 0; q < 4; q++) {                              \
    const int f = q * 4 + w;                                                   \
    if (f < 8) {                                                               \
      const int kgl = sc * 4 + (f >> 1), rg = f & 1;                           \
      glds16(rhbfT + (size_t)(R0 + rg * 16 + l15) * 1024 + (h_)*512 + kgl * 32 + l4 * 8, \
             lds + (kgl * 2 + rg) * 512);                                      \
    } else {                                                                   \
      const int kgl = sc * 4 + ((f - 8) >> 1), cg = (f - 8) & 1;               \
      glds16(WhT + (size_t)(C0B + cg * 16 + l15) * 1024 + (h_)*512 + kgl * 32 + l4 * 8, \
             lds + 16384 + (kgl * 2 + cg) * 512);                              \
    }                                                                          \
  }
#define B_SC(sc)                                                               \
  _Pragma("unroll") for (int k = 0; k < 4; k++) {                              \
    const int kgl = (sc) * 4 + k;                                              \
    const short8 a = *(const short8*)(lds + (kgl * 2 + wm) * 512 + l * 8);     \
    const short8 b = *(const short8*)(lds + 16384 + (kgl * 2 + wn) * 512 + l * 8); \
    acc_c = __builtin_amdgcn_mfma_f32_16x16x32_bf16(a, b, acc_c, 0, 0, 0);     \
  }
      PIN;
      ISSUE_B(0)
      WAIT_VM(12); BAR; PIN; B_SC(0)
      WAIT_VM(8);  BAR; PIN; B_SC(1)
      WAIT_VM(4);  BAR; PIN; B_SC(2)
      WAIT_VM(0);  BAR; PIN; B_SC(3)
      WAIT_LGKM0; BAR;  // WAR guard: all waves done reading half 0
      ISSUE_B(1)
      WAIT_VM(12); BAR; PIN; B_SC(0)
      WAIT_VM(8);  BAR; PIN; B_SC(1)
      WAIT_VM(4);  BAR; PIN; B_SC(2)
      WAIT_VM(0);  BAR; PIN; B_SC(3)
#undef ISSUE_B
#undef B_SC
      unsigned* hbfCu = hbfRu + (size_t)t * 131072;
#pragma unroll
      for (int r = 0; r < 4; r++) {
        const int row = erow0 + r;
        const float cand = tanh_f(acc_c[r] + xpi[r] + bhv);
        const float hn = uu[r] * hp[r] + (1.0f - uu[r]) * cand;
        out[((size_t)row * 64 + t) * 1024 + col] = hn;  // private
        hp[r] = hn;                                     // reg-carried state
        const unsigned mv = (unsigned)f2bf(hn);
        const unsigned ov = (unsigned)__shfl_xor((int)mv, 1, 64);
        if ((l & 1) == 0)
          store_pair_coh(hbfCu + row * 512 + (col >> 1), mv | (ov << 16));
      }
    }
    if (t < 63) {
      // prefetch next step's x-projections under the barrier
      const unsigned short* XPt = XPur + (size_t)(t + 1) * 524288;
#pragma unroll
      for (int r = 0; r < 4; r++) {
        xpu[r] = XPt[(size_t)(erow0 + r) * 2048 + col];
        xpr[r] = XPt[(size_t)(erow0 + r) * 2048 + 1024 + col];
      }
      groupbar(slots + 2 * t + 1);
    }
  }
}

// ---------------------------------------------------------------------------
// Hoisted x-projections GEMM (unchanged).
// ---------------------------------------------------------------------------
DEV void gemm128(const unsigned short* __restrict__ A,
                 const unsigned short* __restrict__ B,
                 int tileM, int tileN, floatx4 (&acc)[4][4]) {
  __shared__ __align__(16) unsigned short lds[2][2][4096];
  const int tid = threadIdx.x;
  const int w = tid >> 6, l = tid & 63;
  const int l15 = l & 15, l4 = l >> 4;
  const int wm = w >> 1, wn = w & 1;

  floatx4 z = {0.f, 0.f, 0.f, 0.f};
#pragma unroll
  for (int i = 0; i < 4; i++)
#pragma unroll
    for (int j = 0; j < 4; j++) acc[i][j] = z;

  const unsigned short* ga0 = A + (size_t)(tileM + w * 16 + l15) * 1024 + l4 * 8;
  const unsigned short* ga1 = ga0 + 64 * 1024;
  const unsigned short* gb0 = B + (size_t)(tileN + w * 16 + l15) * 1024 + l4 * 8;
  const unsigned short* gb1 = gb0 + 64 * 1024;

  glds16(ga0, &lds[0][0][w * 512]);
  glds16(ga1, &lds[0][0][(w + 4) * 512]);
  glds16(gb0, &lds[0][1][w * 512]);
  glds16(gb1, &lds[0][1][(w + 4) * 512]);

#pragma unroll 2
  for (int k0 = 0; k0 < 1024; k0 += 32) {
    const int buf = (k0 >> 5) & 1;
    __syncthreads();
    const int kn = k0 + 32;
    if (kn < 1024) {
      const int nb = buf ^ 1;
      glds16(ga0 + kn, &lds[nb][0][w * 512]);
      glds16(ga1 + kn, &lds[nb][0][(w + 4) * 512]);
      glds16(gb0 + kn, &lds[nb][1][w * 512]);
      glds16(gb1 + kn, &lds[nb][1][(w + 4) * 512]);
    }
    short8 af[4], bfr[4];
    const unsigned short* lA = &lds[buf][0][wm * 2048];
    const unsigned short* lB = &lds[buf][1][wn * 2048];
#pragma unroll
    for (int i = 0; i < 4; i++) af[i] = *(const short8*)(lA + i * 512 + l * 8);
#pragma unroll
    for (int j = 0; j < 4; j++) bfr[j] = *(const short8*)(lB + j * 512 + l * 8);
#pragma unroll
    for (int i = 0; i < 4; i++)
#pragma unroll
      for (int j = 0; j < 4; j++)
        acc[i][j] = __builtin_amdgcn_mfma_f32_16x16x32_bf16(af[i], bfr[j], acc[i][j], 0, 0, 0);
  }
}

__global__ __launch_bounds__(256) void k_pre(
    const unsigned short* __restrict__ Xbf, const unsigned short* __restrict__ Wx,
    unsigned short* __restrict__ XPur, float* __restrict__ out,
    const float* __restrict__ b_iu, const float* __restrict__ b_hu,
    const float* __restrict__ b_ir, const float* __restrict__ b_hr,
    const float* __restrict__ b_i) {
  const int tileN = blockIdx.x * 128;
  const int tileM = blockIdx.y * 128;
  floatx4 acc[4][4];
  gemm128(Xbf, Wx, tileM, tileN, acc);
  const int tid = threadIdx.x;
  const int l = tid & 63;
  const int l15 = l & 15, l4 = l >> 4;
  const int wm = (tid >> 6) >> 1, wn = (tid >> 6) & 1;
#pragma unroll
  for (int i = 0; i < 4; i++)
#pragma unroll
    for (int j = 0; j < 4; j++) {
      const int col = tileN + wn * 64 + j * 16 + l15;
      const int rbase = tileM + wm * 64 + i * 16 + l4 * 4;
#pragma unroll
      for (int r = 0; r < 4; r++) {
        const int row = rbase + r;
        const float v = acc[i][j][r];
        if (col < 2048) {
          const float bias = (col < 1024) ? (b_iu[col] + b_hu[col])
                                          : (b_ir[col - 1024] + b_hr[col - 1024]);
          const int b = row >> 6, t = row & 63;
          XPur[(size_t)((t << 8) | b) * 2048 + col] = f2bf(v + bias);
        } else {
          out[(size_t)row * 1024 + (col - 2048)] = v + b_i[col - 2048];
        }
      }
    }
}

// --------------------------- small helper kernels ---------------------------
__global__ __launch_bounds__(256) void k_conv_txt(const float* __restrict__ x,
                                                  unsigned short* __restrict__ y) {
  const int i = blockIdx.x * 256 + threadIdx.x;
  const float4 v = ((const float4*)x)[i];
  uint2 o;
  o.x = (unsigned)f2bf(v.x) | ((unsigned)f2bf(v.y) << 16);
  o.y = (unsigned)f2bf(v.z) | ((unsigned)f2bf(v.w) << 16);
  ((uint2*)y)[i] = o;
}

__global__ __launch_bounds__(256) void k_conv_w(
    const float* __restrict__ Wiu, const float* __restrict__ Wir, const float* __restrict__ Wi,
    const float* __restrict__ Whu, const float* __restrict__ Whr, const float* __restrict__ Wh,
    unsigned short* __restrict__ Wx, unsigned short* __restrict__ Whh) {
  const int idx = blockIdx.x * 256 + threadIdx.x;
  const int second = idx >= 786432;
  const int id = idx - (second ? 786432 : 0);
  const int n = id >> 8;
  const int kk = (id & 255) << 2;
  const int sel = n >> 10, r = n & 1023;
  const float* src;
  if (second) src = (sel == 0) ? Whu : (sel == 1) ? Whr : Wh;
  else        src = (sel == 0) ? Wiu : (sel == 1) ? Wir : Wi;
  const float4 v = *(const float4*)(src + (size_t)r * 1024 + kk);
  uint2 o;
  o.x = (unsigned)f2bf(v.x) | ((unsigned)f2bf(v.y) << 16);
  o.y = (unsigned)f2bf(v.z) | ((unsigned)f2bf(v.w) << 16);
  unsigned short* dst = second ? Whh : Wx;
  *(uint2*)(dst + (size_t)n * 1024 + kk) = o;
}

// ---------------------------------------------------------------------------
extern "C" void kernel_launch(void* const* d_in, const int* in_sizes, int n_in,
                              void* d_out, int out_size, void* d_ws, size_t ws_size,
                              hipStream_t stream) {
  const float* txt  = (const float*)d_in[0];
  const float* Wiu  = (const float*)d_in[1];
  const float* biu  = (const float*)d_in[2];
  const float* Whu  = (const float*)d_in[3];
  const float* bhu  = (const float*)d_in[4];
  const float* Wir  = (const float*)d_in[5];
  const float* bir  = (const float*)d_in[6];
  const float* Whr  = (const float*)d_in[7];
  const float* bhr  = (const float*)d_in[8];
  const float* Wi   = (const float*)d_in[9];
  const float* bi   = (const float*)d_in[10];
  const float* Wh   = (const float*)d_in[11];
  const float* bh   = (const float*)d_in[12];
  float* out = (float*)d_out;

  char* ws = (char*)d_ws;
  unsigned short* Xbf  = (unsigned short*)(ws);              // 32 MB; reused as hbf ring
  unsigned short* hbfR = Xbf;                                // [64][256][1024] bf16 (write-once per slice)
  unsigned short* Wx   = (unsigned short*)(ws + 33554432);   //  6 MB
  unsigned short* Whhc = (unsigned short*)(ws + 39845888);   //  6 MB (Whu|Whr|Wh)
  unsigned short* XPur = (unsigned short*)(ws + 46137344);   // 64 MB [64][256][2048]
  float*          hbuf = (float*)(ws + 113246208);           //  1 MB (h0 handoff)
  unsigned short* rhbfR= (unsigned short*)(ws + 114294784);  //  8 MB [16][256][1024]
  unsigned*       bar  = (unsigned*)(ws + 122683392);        //  4 KB ticket slots

  hipMemsetAsync((void*)bar, 0, 8 * 128 * 4, stream);

  k_conv_txt<<<16384, 256, 0, stream>>>(txt, Xbf);
  k_conv_w<<<6144, 256, 0, stream>>>(Wiu, Wir, Wi, Whu, Whr, Wh, Wx, Whhc);

  k_pre<<<dim3(24, 128), 256, 0, stream>>>(Xbf, Wx, XPur, out, biu, bhu, bir, bhr, bi);

  // persistent recurrence: reg-resident Bu/Br, reg-carried h, counted-vmcnt
  // pipelined staging; cross-WG state via write-once rings + relaxed
  // agent-scope atomic stores.
  k_recur<<<256, 256, 0, stream>>>(XPur, Whhc, out, hbuf, hbfR, rhbfR, bh, bar);

  (void)in_sizes; (void)n_in; (void)out_size; (void)ws_size;
}